// Round 1
// baseline (1458.080 us; speedup 1.0000x reference)
//
#include <hip/hip_runtime.h>

#define TT 12
#define DD 96
#define WW 96
#define PLANE (DD*WW)      // 9216
#define SP (TT*PLANE)      // 110592
#define F 64

__device__ __forceinline__ float sigmoidf_fast(float x){
    return 1.0f / (1.0f + __expf(-x));
}
__device__ __forceinline__ float tanhf_fast(float x){
    x = fminf(15.0f, fmaxf(-15.0f, x));
    float e = __expf(2.0f * x);
    return (e - 1.0f) / (e + 1.0f);
}

// ---------------------------------------------------------------------------
// Stage A: 3x3 spatial conv over (d,w) with edge (clamp) padding, + bias, relu.
// in:  (CIN, T, D, W)   wgt: (64, CIN, 1, 3, 3)   out: (64, T, D, W)
// Each thread: one spatial position p, NF consecutive out-channels.
// ---------------------------------------------------------------------------
template<int CIN, int NF>
__global__ __launch_bounds__(256) void conv_spatial(
    const float* __restrict__ in, const float* __restrict__ wgt,
    const float* __restrict__ bias, float* __restrict__ out)
{
    const int p  = blockIdx.x * 256 + threadIdx.x;   // 0..SP-1
    const int f0 = blockIdx.y * NF;
    const int t  = p / PLANE;
    const int r  = p - t * PLANE;
    const int d  = r / WW;
    const int w  = r - d * WW;
    const int dm = (d > 0     ? d - 1 : 0);
    const int dp = (d < DD-1  ? d + 1 : DD-1);
    const int wm = (w > 0     ? w - 1 : 0);
    const int wp = (w < WW-1  ? w + 1 : WW-1);

    float acc[NF];
    #pragma unroll
    for (int j = 0; j < NF; j++) acc[j] = 0.f;

    const int base = t * PLANE;
    for (int c = 0; c < CIN; c++) {
        const float* ip = in + c * SP + base;
        const float v0 = ip[dm*WW+wm], v1 = ip[dm*WW+w], v2 = ip[dm*WW+wp];
        const float v3 = ip[d *WW+wm], v4 = ip[d *WW+w], v5 = ip[d *WW+wp];
        const float v6 = ip[dp*WW+wm], v7 = ip[dp*WW+w], v8 = ip[dp*WW+wp];
        #pragma unroll
        for (int j = 0; j < NF; j++) {
            const float* wj = wgt + ((f0 + j) * CIN + c) * 9;  // uniform -> s_load
            acc[j] += v0*wj[0] + v1*wj[1] + v2*wj[2]
                    + v3*wj[3] + v4*wj[4] + v5*wj[5]
                    + v6*wj[6] + v7*wj[7] + v8*wj[8];
        }
    }
    #pragma unroll
    for (int j = 0; j < NF; j++) {
        float val = acc[j] + bias[f0 + j];
        out[(f0 + j) * SP + p] = fmaxf(val, 0.f);
    }
}

// ---------------------------------------------------------------------------
// Stage B: 3-tap temporal conv over t with wrap padding, + bias, optional relu.
// in: (64, T, D, W)   wgt: (COUT, 64, 3, 1, 1)   out: (COUT, T, D, W)
// Each thread: one (d,w) position, all 12 t, NF out-channels.
// ---------------------------------------------------------------------------
template<int COUT, int NF, bool RELU>
__global__ __launch_bounds__(256) void conv_temporal(
    const float* __restrict__ in, const float* __restrict__ wgt,
    const float* __restrict__ bias, float* __restrict__ out)
{
    const int p2 = blockIdx.x * 256 + threadIdx.x;   // 0..PLANE-1
    const int f0 = blockIdx.y * NF;

    float acc[TT][NF];
    #pragma unroll
    for (int t = 0; t < TT; t++)
        #pragma unroll
        for (int j = 0; j < NF; j++) acc[t][j] = 0.f;

    for (int c = 0; c < F; c++) {
        const float* ip = in + c * SP + p2;
        float xv[TT];
        #pragma unroll
        for (int t = 0; t < TT; t++) xv[t] = ip[t * PLANE];
        #pragma unroll
        for (int j = 0; j < NF; j++) {
            const float* wj = wgt + ((f0 + j) * F + c) * 3;  // uniform -> s_load
            const float w0 = wj[0], w1 = wj[1], w2 = wj[2];
            #pragma unroll
            for (int t = 0; t < TT; t++) {
                acc[t][j] += xv[(t + TT - 1) % TT] * w0
                           + xv[t]                * w1
                           + xv[(t + 1) % TT]     * w2;
            }
        }
    }
    #pragma unroll
    for (int j = 0; j < NF; j++) {
        const float b = bias[f0 + j];
        #pragma unroll
        for (int t = 0; t < TT; t++) {
            float val = acc[t][j] + b;
            if (RELU) val = fmaxf(val, 0.f);
            out[(f0 + j) * SP + t * PLANE + p2] = val;
        }
    }
}

// ---------------------------------------------------------------------------
// LRU (GRU-like). Per position p: gi = Wih @ x[:,p] + bih ; gh = Whh @ h[:,p]
// slices (r_i, r_h, z_i, z_h, c_i, c_h). Each thread: one p, 8 channels.
// ---------------------------------------------------------------------------
__global__ __launch_bounds__(256) void lru_kernel(
    const float* __restrict__ x,   const float* __restrict__ h,
    const float* __restrict__ wih, const float* __restrict__ bih,
    const float* __restrict__ whh, const float* __restrict__ bh,
    float* __restrict__ out, float* __restrict__ hnew)
{
    constexpr int NF = 8;
    const int p  = blockIdx.x * 256 + threadIdx.x;  // 0..SP-1
    const int f0 = blockIdx.y * NF;

    float a_r[NF], a_rh[NF], a_z[NF], a_zh[NF];
    float gi4[NF], gh4[NF], gi5[NF], gh5[NF];
    #pragma unroll
    for (int j = 0; j < NF; j++) {
        a_r[j] = a_rh[j] = a_z[j] = a_zh[j] = 0.f;
        gi4[j] = gh4[j] = gi5[j] = gh5[j] = 0.f;
    }

    for (int i = 0; i < F; i++) {
        const float xv = x[i * SP + p];
        const float hv = h[i * SP + p];
        #pragma unroll
        for (int j = 0; j < NF; j++) {
            const int f = f0 + j;
            a_r[j]  += wih[(0*F + f)*F + i] * xv + whh[(0*F + f)*F + i] * hv;
            a_rh[j] += wih[(1*F + f)*F + i] * xv + whh[(1*F + f)*F + i] * hv;
            a_z[j]  += wih[(2*F + f)*F + i] * xv + whh[(2*F + f)*F + i] * hv;
            a_zh[j] += wih[(3*F + f)*F + i] * xv + whh[(3*F + f)*F + i] * hv;
            gi4[j]  += wih[(4*F + f)*F + i] * xv;
            gh4[j]  += whh[(4*F + f)*F + i] * hv;
            gi5[j]  += wih[(5*F + f)*F + i] * xv;
            gh5[j]  += whh[(5*F + f)*F + i] * hv;
        }
    }

    #pragma unroll
    for (int j = 0; j < NF; j++) {
        const int f = f0 + j;
        const float xf = x[f * SP + p];
        const float hf = h[f * SP + p];
        const float ri = sigmoidf_fast(a_r[j]  + bih[0*F + f]);
        const float rh = sigmoidf_fast(a_rh[j] + bih[1*F + f]);
        const float zi = sigmoidf_fast(a_z[j]  + bih[2*F + f]);
        const float zh = sigmoidf_fast(a_zh[j] + bih[3*F + f]);
        const float ci = tanhf_fast(gi5[j] + bih[5*F + f] + rh * (gh5[j] + bh[f]));
        const float ch = tanhf_fast(ri * (gi4[j] + bih[4*F + f]) + gh4[j]);
        out [f * SP + p] = zi * ch + (1.0f - zi) * xf;
        hnew[f * SP + p] = zh * ci + (1.0f - zh) * hf;
    }
}

// ---------------------------------------------------------------------------
extern "C" void kernel_launch(void* const* d_in, const int* in_sizes, int n_in,
                              void* d_out, int out_size, void* d_ws, size_t ws_size,
                              hipStream_t stream) {
    const float* x       = (const float*)d_in[0];
    const float* h1      = (const float*)d_in[1];
    const float* h2      = (const float*)d_in[2];
    const float* win_w1  = (const float*)d_in[3];
    const float* win_b1  = (const float*)d_in[4];
    const float* win_w2  = (const float*)d_in[5];
    const float* win_b2  = (const float*)d_in[6];
    const float* r1_wih  = (const float*)d_in[7];
    const float* r1_bih  = (const float*)d_in[8];
    const float* r1_whh  = (const float*)d_in[9];
    const float* r1_bh   = (const float*)d_in[10];
    const float* wbt_w1  = (const float*)d_in[11];
    const float* wbt_b1  = (const float*)d_in[12];
    const float* wbt_w2  = (const float*)d_in[13];
    const float* wbt_b2  = (const float*)d_in[14];
    const float* r2_wih  = (const float*)d_in[15];
    const float* r2_bih  = (const float*)d_in[16];
    const float* r2_whh  = (const float*)d_in[17];
    const float* r2_bh   = (const float*)d_in[18];
    const float* wout_w1 = (const float*)d_in[19];
    const float* wout_b1 = (const float*)d_in[20];
    const float* wout_w2 = (const float*)d_in[21];
    const float* wout_b2 = (const float*)d_in[22];

    float* eta_out = (float*)d_out;                       // 2*SP
    float* h1n_out = eta_out + 2 * SP;                    // 64*SP
    float* h2n_out = h1n_out + F * SP;                    // 64*SP

    float* bufA = (float*)d_ws;
    float* bufB = bufA + (size_t)F * SP;

    const dim3 blk(256);
    const dim3 gA(SP / 256, F / 8);       // conv_spatial, NF=8
    const dim3 gB(PLANE / 256, F / 8);    // conv_temporal, NF=8
    const dim3 gL(SP / 256, F / 8);       // lru, NF=8

    // block 1 (win): 4 -> 64
    conv_spatial<4, 8><<<gA, blk, 0, stream>>>(x, win_w1, win_b1, bufA);
    conv_temporal<64, 8, true><<<gB, blk, 0, stream>>>(bufA, win_w2, win_b2, bufB);
    // LRU 1: y=bufB, h1 -> out=bufA, hnew=h1n
    lru_kernel<<<gL, blk, 0, stream>>>(bufB, h1, r1_wih, r1_bih, r1_whh, r1_bh,
                                       bufA, h1n_out);
    // block 2 (wbt): 64 -> 64
    conv_spatial<64, 8><<<gA, blk, 0, stream>>>(bufA, wbt_w1, wbt_b1, bufB);
    conv_temporal<64, 8, true><<<gB, blk, 0, stream>>>(bufB, wbt_w2, wbt_b2, bufA);
    // LRU 2: y=bufA, h2 -> out=bufB, hnew=h2n
    lru_kernel<<<gL, blk, 0, stream>>>(bufA, h2, r2_wih, r2_bih, r2_whh, r2_bh,
                                       bufB, h2n_out);
    // block 3 (wout): 64 -> 64 -> 2, no final relu
    conv_spatial<64, 8><<<gA, blk, 0, stream>>>(bufB, wout_w1, wout_b1, bufA);
    conv_temporal<2, 2, false><<<dim3(PLANE / 256, 1), blk, 0, stream>>>(
        bufA, wout_w2, wout_b2, eta_out);
}

// Round 2
// 1140.016 us; speedup vs baseline: 1.2790x; 1.2790x over previous
//
#include <hip/hip_runtime.h>

#define TT 12
#define DD 96
#define WW 96
#define PLANE (DD*WW)      // 9216
#define SP (TT*PLANE)      // 110592
#define F 64

__device__ __forceinline__ float sigmoidf_fast(float x){
    return 1.0f / (1.0f + __expf(-x));
}
__device__ __forceinline__ float tanhf_fast(float x){
    x = fminf(15.0f, fmaxf(-15.0f, x));
    float e = __expf(2.0f * x);
    return (e - 1.0f) / (e + 1.0f);
}

// ---------------------------------------------------------------------------
// Weight repack kernels (run every call; tiny, deterministic).
// ---------------------------------------------------------------------------
// LRU: wih,whh (6F x F) -> wp[i][g][f], g in 0..11 (0-5: wih, 6-11: whh)
__global__ __launch_bounds__(256) void repack_lru(
    const float* __restrict__ wih, const float* __restrict__ whh,
    float* __restrict__ wp)
{
    const int idx = blockIdx.x * 256 + threadIdx.x;  // 64*12*64 = 49152
    const int f = idx & 63;
    const int g = (idx >> 6) % 12;
    const int i = idx / (12 * 64);
    wp[idx] = (g < 6) ? wih[(g * F + f) * F + i]
                      : whh[((g - 6) * F + f) * F + i];
}

// spatial conv: wgt (64, CIN, 1, 3, 3) -> wp[c][tap][f]
template<int CIN>
__global__ __launch_bounds__(256) void repack_sp(
    const float* __restrict__ wgt, float* __restrict__ wp)
{
    const int idx = blockIdx.x * 256 + threadIdx.x;  // CIN*9*64
    if (idx >= CIN * 9 * 64) return;
    const int f = idx & 63;
    const int tap = (idx >> 6) % 9;
    const int c = idx / (9 * 64);
    wp[idx] = wgt[((f * CIN) + c) * 9 + tap];
}

// temporal conv: wgt (64, 64, 3) -> wp[c][tap][f]
__global__ __launch_bounds__(256) void repack_tm(
    const float* __restrict__ wgt, float* __restrict__ wp)
{
    const int idx = blockIdx.x * 256 + threadIdx.x;  // 64*3*64 = 12288
    const int f = idx & 63;
    const int tap = (idx >> 6) % 3;
    const int c = idx / (3 * 64);
    wp[idx] = wgt[(f * F + c) * 3 + tap];
}

// ---------------------------------------------------------------------------
// Stage A: 3x3 spatial conv (edge pad) + bias + relu. Repacked weights.
// in: (CIN,T,D,W)  wp: [CIN][9][64]  out: (64,T,D,W)
// ---------------------------------------------------------------------------
template<int CIN, int NF>
__global__ __launch_bounds__(256) void conv_spatial2(
    const float* __restrict__ in, const float* __restrict__ wp_,
    const float* __restrict__ bias, float* __restrict__ out)
{
    const float* wp = (const float*)__builtin_assume_aligned(wp_, 64);
    const int p  = blockIdx.x * 256 + threadIdx.x;
    const int f0 = blockIdx.y * NF;
    const int t  = p / PLANE;
    const int r  = p - t * PLANE;
    const int d  = r / WW;
    const int w  = r - d * WW;
    const int dm = (d > 0    ? d - 1 : 0);
    const int dp = (d < DD-1 ? d + 1 : DD-1);
    const int wm = (w > 0    ? w - 1 : 0);
    const int wpx= (w < WW-1 ? w + 1 : WW-1);

    float acc[NF];
    #pragma unroll
    for (int j = 0; j < NF; j++) acc[j] = 0.f;

    const int base = t * PLANE;
    for (int c = 0; c < CIN; c++) {
        const float* ip = in + c * SP + base;
        const float v0 = ip[dm*WW+wm], v1 = ip[dm*WW+w], v2 = ip[dm*WW+wpx];
        const float v3 = ip[d *WW+wm], v4 = ip[d *WW+w], v5 = ip[d *WW+wpx];
        const float v6 = ip[dp*WW+wm], v7 = ip[dp*WW+w], v8 = ip[dp*WW+wpx];
        const float* wr = wp + c * 9 * 64 + f0;
        #pragma unroll
        for (int j = 0; j < NF; j++) {
            acc[j] += v0*wr[0*64+j] + v1*wr[1*64+j] + v2*wr[2*64+j]
                    + v3*wr[3*64+j] + v4*wr[4*64+j] + v5*wr[5*64+j]
                    + v6*wr[6*64+j] + v7*wr[7*64+j] + v8*wr[8*64+j];
        }
    }
    #pragma unroll
    for (int j = 0; j < NF; j++) {
        float val = acc[j] + bias[f0 + j];
        out[(f0 + j) * SP + p] = fmaxf(val, 0.f);
    }
}

// ---------------------------------------------------------------------------
// Stage B: 3-tap temporal conv (wrap pad) + bias + relu. Repacked weights.
// in: (64,T,D,W)  wp: [64][3][64]  out: (64,T,D,W)
// ---------------------------------------------------------------------------
template<int NF>
__global__ __launch_bounds__(256) void conv_temporal2(
    const float* __restrict__ in, const float* __restrict__ wp_,
    const float* __restrict__ bias, float* __restrict__ out)
{
    const float* wp = (const float*)__builtin_assume_aligned(wp_, 64);
    const int p2 = blockIdx.x * 256 + threadIdx.x;   // 0..PLANE-1
    const int f0 = blockIdx.y * NF;

    float acc[TT][NF];
    #pragma unroll
    for (int t = 0; t < TT; t++)
        #pragma unroll
        for (int j = 0; j < NF; j++) acc[t][j] = 0.f;

    for (int c = 0; c < F; c++) {
        const float* ip = in + c * SP + p2;
        float xv[TT];
        #pragma unroll
        for (int t = 0; t < TT; t++) xv[t] = ip[t * PLANE];
        const float* wr = wp + c * 3 * 64 + f0;
        #pragma unroll
        for (int j = 0; j < NF; j++) {
            const float w0 = wr[0*64+j], w1 = wr[1*64+j], w2 = wr[2*64+j];
            #pragma unroll
            for (int t = 0; t < TT; t++) {
                acc[t][j] += xv[(t + TT - 1) % TT] * w0
                           + xv[t]                * w1
                           + xv[(t + 1) % TT]     * w2;
            }
        }
    }
    #pragma unroll
    for (int j = 0; j < NF; j++) {
        const float b = bias[f0 + j];
        #pragma unroll
        for (int t = 0; t < TT; t++) {
            out[(f0 + j) * SP + t * PLANE + p2] = fmaxf(acc[t][j] + b, 0.f);
        }
    }
}

// ---------------------------------------------------------------------------
// Final temporal conv, COUT=2, no relu, original weight layout (2,64,3).
// ---------------------------------------------------------------------------
__global__ __launch_bounds__(256) void conv_temporal_out(
    const float* __restrict__ in, const float* __restrict__ wgt,
    const float* __restrict__ bias, float* __restrict__ out)
{
    constexpr int NF = 2;
    const int p2 = blockIdx.x * 256 + threadIdx.x;

    float acc[TT][NF];
    #pragma unroll
    for (int t = 0; t < TT; t++)
        #pragma unroll
        for (int j = 0; j < NF; j++) acc[t][j] = 0.f;

    for (int c = 0; c < F; c++) {
        const float* ip = in + c * SP + p2;
        float xv[TT];
        #pragma unroll
        for (int t = 0; t < TT; t++) xv[t] = ip[t * PLANE];
        #pragma unroll
        for (int j = 0; j < NF; j++) {
            const float* wj = wgt + (j * F + c) * 3;
            const float w0 = wj[0], w1 = wj[1], w2 = wj[2];
            #pragma unroll
            for (int t = 0; t < TT; t++) {
                acc[t][j] += xv[(t + TT - 1) % TT] * w0
                           + xv[t]                * w1
                           + xv[(t + 1) % TT]     * w2;
            }
        }
    }
    #pragma unroll
    for (int j = 0; j < NF; j++) {
        const float b = bias[j];
        #pragma unroll
        for (int t = 0; t < TT; t++)
            out[j * SP + t * PLANE + p2] = acc[t][j] + b;
    }
}

// ---------------------------------------------------------------------------
// LRU v2: repacked weights wp[i][g][f], NP positions per thread.
// ---------------------------------------------------------------------------
template<int NP>
__global__ __launch_bounds__(256) void lru_v2(
    const float* __restrict__ x,   const float* __restrict__ h,
    const float* __restrict__ wp_, const float* __restrict__ bih,
    const float* __restrict__ bh,
    float* __restrict__ out, float* __restrict__ hnew)
{
    constexpr int NF = 8;
    const float* wp = (const float*)__builtin_assume_aligned(wp_, 64);
    const int tid = threadIdx.x;
    const int p0  = blockIdx.x * (256 * NP) + tid;
    const int f0  = blockIdx.y * NF;

    float a0[NF][NP], a1[NF][NP], a2[NF][NP], a3[NF][NP];
    float gi4[NF][NP], gh4[NF][NP], gi5[NF][NP], gh5[NF][NP];
    #pragma unroll
    for (int j = 0; j < NF; j++)
        #pragma unroll
        for (int q = 0; q < NP; q++) {
            a0[j][q] = a1[j][q] = a2[j][q] = a3[j][q] = 0.f;
            gi4[j][q] = gh4[j][q] = gi5[j][q] = gh5[j][q] = 0.f;
        }

    for (int i = 0; i < F; i++) {
        float xv[NP], hv[NP];
        #pragma unroll
        for (int q = 0; q < NP; q++) {
            xv[q] = x[i * SP + p0 + q * 256];
            hv[q] = h[i * SP + p0 + q * 256];
        }
        const float* w = wp + i * (12 * 64) + f0;
        #pragma unroll
        for (int j = 0; j < NF; j++) {
            const float w0 = w[ 0*64+j], w1 = w[ 1*64+j], w2 = w[ 2*64+j];
            const float w3 = w[ 3*64+j], w4 = w[ 4*64+j], w5 = w[ 5*64+j];
            const float w6 = w[ 6*64+j], w7 = w[ 7*64+j], w8 = w[ 8*64+j];
            const float w9 = w[ 9*64+j], wa = w[10*64+j], wb = w[11*64+j];
            #pragma unroll
            for (int q = 0; q < NP; q++) {
                a0[j][q]  += w0 * xv[q] + w6 * hv[q];
                a1[j][q]  += w1 * xv[q] + w7 * hv[q];
                a2[j][q]  += w2 * xv[q] + w8 * hv[q];
                a3[j][q]  += w3 * xv[q] + w9 * hv[q];
                gi4[j][q] += w4 * xv[q];
                gh4[j][q] += wa * hv[q];
                gi5[j][q] += w5 * xv[q];
                gh5[j][q] += wb * hv[q];
            }
        }
    }

    #pragma unroll
    for (int j = 0; j < NF; j++) {
        const int f = f0 + j;
        const float b0 = bih[0*F+f], b1 = bih[1*F+f], b2 = bih[2*F+f];
        const float b3 = bih[3*F+f], b4 = bih[4*F+f], b5 = bih[5*F+f];
        const float bhf = bh[f];
        #pragma unroll
        for (int q = 0; q < NP; q++) {
            const int p = p0 + q * 256;
            const float xf = x[f * SP + p];
            const float hf = h[f * SP + p];
            const float ri = sigmoidf_fast(a0[j][q] + b0);
            const float rh = sigmoidf_fast(a1[j][q] + b1);
            const float zi = sigmoidf_fast(a2[j][q] + b2);
            const float zh = sigmoidf_fast(a3[j][q] + b3);
            const float ci = tanhf_fast(gi5[j][q] + b5 + rh * (gh5[j][q] + bhf));
            const float ch = tanhf_fast(ri * (gi4[j][q] + b4) + gh4[j][q]);
            out [f * SP + p] = zi * ch + (1.0f - zi) * xf;
            hnew[f * SP + p] = zh * ci + (1.0f - zh) * hf;
        }
    }
}

// ---------------------------------------------------------------------------
extern "C" void kernel_launch(void* const* d_in, const int* in_sizes, int n_in,
                              void* d_out, int out_size, void* d_ws, size_t ws_size,
                              hipStream_t stream) {
    const float* x       = (const float*)d_in[0];
    const float* h1      = (const float*)d_in[1];
    const float* h2      = (const float*)d_in[2];
    const float* win_w1  = (const float*)d_in[3];
    const float* win_b1  = (const float*)d_in[4];
    const float* win_w2  = (const float*)d_in[5];
    const float* win_b2  = (const float*)d_in[6];
    const float* r1_wih  = (const float*)d_in[7];
    const float* r1_bih  = (const float*)d_in[8];
    const float* r1_whh  = (const float*)d_in[9];
    const float* r1_bh   = (const float*)d_in[10];
    const float* wbt_w1  = (const float*)d_in[11];
    const float* wbt_b1  = (const float*)d_in[12];
    const float* wbt_w2  = (const float*)d_in[13];
    const float* wbt_b2  = (const float*)d_in[14];
    const float* r2_wih  = (const float*)d_in[15];
    const float* r2_bih  = (const float*)d_in[16];
    const float* r2_whh  = (const float*)d_in[17];
    const float* r2_bh   = (const float*)d_in[18];
    const float* wout_w1 = (const float*)d_in[19];
    const float* wout_b1 = (const float*)d_in[20];
    const float* wout_w2 = (const float*)d_in[21];
    const float* wout_b2 = (const float*)d_in[22];

    float* eta_out = (float*)d_out;                       // 2*SP
    float* h1n_out = eta_out + 2 * SP;                    // 64*SP
    float* h2n_out = h1n_out + F * SP;                    // 64*SP

    float* bufA = (float*)d_ws;
    float* bufB = bufA + (size_t)F * SP;

    // Repacked weights live in the eta region of d_out (2*SP floats =
    // 221184 floats). It is dead until the final kernel overwrites it.
    float* lru1_p  = eta_out;              // 49152
    float* lru2_p  = eta_out + 49152;      // 49152
    float* wbt1_p  = eta_out + 98304;      // 36864
    float* wout1_p = eta_out + 135168;     // 36864
    float* win1_p  = eta_out + 172032;     // 2304
    float* win2_p  = eta_out + 174336;     // 12288
    float* wbt2_p  = eta_out + 186624;     // 12288 (ends 198912 < 221184)

    const dim3 blk(256);

    // --- repacks ---
    repack_lru<<<192, blk, 0, stream>>>(r1_wih, r1_whh, lru1_p);
    repack_lru<<<192, blk, 0, stream>>>(r2_wih, r2_whh, lru2_p);
    repack_sp<64><<<144, blk, 0, stream>>>(wbt_w1, wbt1_p);
    repack_sp<64><<<144, blk, 0, stream>>>(wout_w1, wout1_p);
    repack_sp<4><<<9, blk, 0, stream>>>(win_w1, win1_p);
    repack_tm<<<48, blk, 0, stream>>>(win_w2, win2_p);
    repack_tm<<<48, blk, 0, stream>>>(wbt_w2, wbt2_p);

    const dim3 gA(SP / 256, F / 8);         // conv_spatial2, NF=8
    const dim3 gB(PLANE / 256, F / 8);      // conv_temporal2, NF=8
    const dim3 gL(SP / 512, F / 8);         // lru_v2, NP=2

    // block 1 (win): 4 -> 64
    conv_spatial2<4, 8><<<gA, blk, 0, stream>>>(x, win1_p, win_b1, bufA);
    conv_temporal2<8><<<gB, blk, 0, stream>>>(bufA, win2_p, win_b2, bufB);
    // LRU 1: y=bufB, h1 -> out=bufA, hnew=h1n
    lru_v2<2><<<gL, blk, 0, stream>>>(bufB, h1, lru1_p, r1_bih, r1_bh,
                                      bufA, h1n_out);
    // block 2 (wbt): 64 -> 64
    conv_spatial2<64, 8><<<gA, blk, 0, stream>>>(bufA, wbt1_p, wbt_b1, bufB);
    conv_temporal2<8><<<gB, blk, 0, stream>>>(bufB, wbt2_p, wbt_b2, bufA);
    // LRU 2: y=bufA, h2 -> out=bufB, hnew=h2n
    lru_v2<2><<<gL, blk, 0, stream>>>(bufA, h2, lru2_p, r2_bih, r2_bh,
                                      bufB, h2n_out);
    // block 3 (wout): 64 -> 64 -> 2, no final relu
    conv_spatial2<64, 8><<<gA, blk, 0, stream>>>(bufB, wout1_p, wout_b1, bufA);
    conv_temporal_out<<<dim3(PLANE / 256), blk, 0, stream>>>(
        bufA, wout_w2, wout_b2, eta_out);
}

// Round 3
// 600.872 us; speedup vs baseline: 2.4266x; 1.8973x over previous
//
#include <hip/hip_runtime.h>

#define TT 12
#define DD 96
#define WW 96
#define PLANE (DD*WW)      // 9216
#define SP (TT*PLANE)      // 110592
#define F 64

typedef short bf16x8 __attribute__((ext_vector_type(8)));
typedef float f32x4  __attribute__((ext_vector_type(4)));

__device__ __forceinline__ float sigmoidf_fast(float x){
    return 1.0f / (1.0f + __expf(-x));
}
__device__ __forceinline__ float tanhf_fast(float x){
    x = fminf(15.0f, fmaxf(-15.0f, x));
    float e = __expf(2.0f * x);
    return (e - 1.0f) / (e + 1.0f);
}
__device__ __forceinline__ unsigned short f2bf(float x){
    unsigned int u = __float_as_uint(x);
    u = (u + 0x7FFFu + ((u >> 16) & 1u)) >> 16;   // RNE
    return (unsigned short)u;
}

// ---------------------------------------------------------------------------
// Repack kernels
// ---------------------------------------------------------------------------
// LRU weights -> bf16 MFMA A-fragments.
// frag id = (fhi*12 + t)*2 + ks ; t in 0..5 = Wih gate t, 6..11 = Whh gate t-6.
// element = lane*8 + j ; A[row=lane&15][k=(lane>>4)*8+j] ;
// m = gate*64 + fhi*16 + (lane&15) ; kk = ks*32 + (lane>>4)*8 + j.
__global__ __launch_bounds__(256) void repack_lru_frag(
    const float* __restrict__ wih, const float* __restrict__ whh,
    unsigned short* __restrict__ awp)
{
    const int idx  = blockIdx.x * 256 + threadIdx.x;  // 4*12*2*512 = 49152
    const int j    = idx & 7;
    const int lane = (idx >> 3) & 63;
    const int frag = idx >> 9;
    const int ks   = frag & 1;
    const int t    = (frag >> 1) % 12;
    const int fhi  = frag / 24;
    const int g    = (t < 6) ? t : t - 6;
    const int m    = g * 64 + fhi * 16 + (lane & 15);
    const int kk   = ks * 32 + (lane >> 4) * 8 + j;
    const float v  = (t < 6) ? wih[m * F + kk] : whh[m * F + kk];
    awp[idx] = f2bf(v);
}

// spatial conv: wgt (64, CIN, 1, 3, 3) -> wp[c][tap][f]
template<int CIN>
__global__ __launch_bounds__(256) void repack_sp(
    const float* __restrict__ wgt, float* __restrict__ wp)
{
    const int idx = blockIdx.x * 256 + threadIdx.x;  // CIN*9*64
    if (idx >= CIN * 9 * 64) return;
    const int f = idx & 63;
    const int tap = (idx >> 6) % 9;
    const int c = idx / (9 * 64);
    wp[idx] = wgt[((f * CIN) + c) * 9 + tap];
}

// temporal conv: wgt (64, 64, 3) -> wp[c][tap][f]
__global__ __launch_bounds__(256) void repack_tm(
    const float* __restrict__ wgt, float* __restrict__ wp)
{
    const int idx = blockIdx.x * 256 + threadIdx.x;  // 64*3*64 = 12288
    const int f = idx & 63;
    const int tap = (idx >> 6) % 3;
    const int c = idx / (3 * 64);
    wp[idx] = wgt[(f * F + c) * 3 + tap];
}

// ---------------------------------------------------------------------------
// Stage A: 3x3 spatial conv (edge pad) + bias + relu. Repacked weights.
// ---------------------------------------------------------------------------
template<int CIN, int NF>
__global__ __launch_bounds__(256) void conv_spatial2(
    const float* __restrict__ in, const float* __restrict__ wp_,
    const float* __restrict__ bias, float* __restrict__ out)
{
    const float* wp = (const float*)__builtin_assume_aligned(wp_, 64);
    const int p  = blockIdx.x * 256 + threadIdx.x;
    const int f0 = blockIdx.y * NF;
    const int t  = p / PLANE;
    const int r  = p - t * PLANE;
    const int d  = r / WW;
    const int w  = r - d * WW;
    const int dm = (d > 0    ? d - 1 : 0);
    const int dp = (d < DD-1 ? d + 1 : DD-1);
    const int wm = (w > 0    ? w - 1 : 0);
    const int wpx= (w < WW-1 ? w + 1 : WW-1);

    float acc[NF];
    #pragma unroll
    for (int j = 0; j < NF; j++) acc[j] = 0.f;

    const int base = t * PLANE;
    for (int c = 0; c < CIN; c++) {
        const float* ip = in + c * SP + base;
        const float v0 = ip[dm*WW+wm], v1 = ip[dm*WW+w], v2 = ip[dm*WW+wpx];
        const float v3 = ip[d *WW+wm], v4 = ip[d *WW+w], v5 = ip[d *WW+wpx];
        const float v6 = ip[dp*WW+wm], v7 = ip[dp*WW+w], v8 = ip[dp*WW+wpx];
        const float* wr = wp + c * 9 * 64 + f0;
        #pragma unroll
        for (int j = 0; j < NF; j++) {
            acc[j] += v0*wr[0*64+j] + v1*wr[1*64+j] + v2*wr[2*64+j]
                    + v3*wr[3*64+j] + v4*wr[4*64+j] + v5*wr[5*64+j]
                    + v6*wr[6*64+j] + v7*wr[7*64+j] + v8*wr[8*64+j];
        }
    }
    #pragma unroll
    for (int j = 0; j < NF; j++) {
        float val = acc[j] + bias[f0 + j];
        out[(f0 + j) * SP + p] = fmaxf(val, 0.f);
    }
}

// ---------------------------------------------------------------------------
// Stage B: 3-tap temporal conv (wrap pad) + bias + relu. Repacked weights.
// ---------------------------------------------------------------------------
template<int NF>
__global__ __launch_bounds__(256) void conv_temporal2(
    const float* __restrict__ in, const float* __restrict__ wp_,
    const float* __restrict__ bias, float* __restrict__ out)
{
    const float* wp = (const float*)__builtin_assume_aligned(wp_, 64);
    const int p2 = blockIdx.x * 256 + threadIdx.x;   // 0..PLANE-1
    const int f0 = blockIdx.y * NF;

    float acc[TT][NF];
    #pragma unroll
    for (int t = 0; t < TT; t++)
        #pragma unroll
        for (int j = 0; j < NF; j++) acc[t][j] = 0.f;

    for (int c = 0; c < F; c++) {
        const float* ip = in + c * SP + p2;
        float xv[TT];
        #pragma unroll
        for (int t = 0; t < TT; t++) xv[t] = ip[t * PLANE];
        const float* wr = wp + c * 3 * 64 + f0;
        #pragma unroll
        for (int j = 0; j < NF; j++) {
            const float w0 = wr[0*64+j], w1 = wr[1*64+j], w2 = wr[2*64+j];
            #pragma unroll
            for (int t = 0; t < TT; t++) {
                acc[t][j] += xv[(t + TT - 1) % TT] * w0
                           + xv[t]                * w1
                           + xv[(t + 1) % TT]     * w2;
            }
        }
    }
    #pragma unroll
    for (int j = 0; j < NF; j++) {
        const float b = bias[f0 + j];
        #pragma unroll
        for (int t = 0; t < TT; t++) {
            out[(f0 + j) * SP + t * PLANE + p2] = fmaxf(acc[t][j] + b, 0.f);
        }
    }
}

// ---------------------------------------------------------------------------
// Final temporal conv, COUT=2, no relu, original weight layout (2,64,3).
// ---------------------------------------------------------------------------
__global__ __launch_bounds__(256) void conv_temporal_out(
    const float* __restrict__ in, const float* __restrict__ wgt,
    const float* __restrict__ bias, float* __restrict__ out)
{
    constexpr int NF = 2;
    const int p2 = blockIdx.x * 256 + threadIdx.x;

    float acc[TT][NF];
    #pragma unroll
    for (int t = 0; t < TT; t++)
        #pragma unroll
        for (int j = 0; j < NF; j++) acc[t][j] = 0.f;

    for (int c = 0; c < F; c++) {
        const float* ip = in + c * SP + p2;
        float xv[TT];
        #pragma unroll
        for (int t = 0; t < TT; t++) xv[t] = ip[t * PLANE];
        #pragma unroll
        for (int j = 0; j < NF; j++) {
            const float* wj = wgt + (j * F + c) * 3;
            const float w0 = wj[0], w1 = wj[1], w2 = wj[2];
            #pragma unroll
            for (int t = 0; t < TT; t++) {
                acc[t][j] += xv[(t + TT - 1) % TT] * w0
                           + xv[t]                * w1
                           + xv[(t + 1) % TT]     * w2;
            }
        }
    }
    #pragma unroll
    for (int j = 0; j < NF; j++) {
        const float b = bias[j];
        #pragma unroll
        for (int t = 0; t < TT; t++)
            out[j * SP + t * PLANE + p2] = acc[t][j] + b;
    }
}

// ---------------------------------------------------------------------------
// LRU via MFMA. gi = Wih@x + bih ; gh = Whh@h ; GEMM M=384,K=64 (x2), fused
// GRU pointwise. A = fragment-ordered bf16 weights (awp). Each wave: 32
// positions (2 n-tiles). C layout: col=lane&15, row=(lane>>4)*4+reg -> all 12
// gate values of (f,p) live in ONE thread.
// ---------------------------------------------------------------------------
__global__ __launch_bounds__(256) void lru_mfma(
    const float* __restrict__ x, const float* __restrict__ h,
    const unsigned short* __restrict__ awp,
    const float* __restrict__ bih, const float* __restrict__ bh,
    float* __restrict__ out, float* __restrict__ hnew)
{
    const int tid  = threadIdx.x;
    const int wave = tid >> 6;
    const int lane = tid & 63;
    const int col  = lane & 15;
    const int kg   = lane >> 4;
    const int p0   = (blockIdx.x * 4 + wave) * 32;

    // B fragments: B[k=(lane>>4)*8+j][n=col], k global = ks*32 + kg*8 + j
    bf16x8 bx[2][2], bhv[2][2];
    #pragma unroll
    for (int ks = 0; ks < 2; ks++) {
        #pragma unroll
        for (int nt = 0; nt < 2; nt++) {
            const int pb = p0 + nt * 16 + col;
            bf16x8 vx, vh;
            #pragma unroll
            for (int j = 0; j < 8; j++) {
                const int k = ks * 32 + kg * 8 + j;
                vx[j] = (short)f2bf(x[k * SP + pb]);
                vh[j] = (short)f2bf(h[k * SP + pb]);
            }
            bx[ks][nt] = vx;
            bhv[ks][nt] = vh;
        }
    }

    #pragma unroll
    for (int fhi = 0; fhi < 4; fhi++) {
        f32x4 acc[12][2];
        #pragma unroll
        for (int t = 0; t < 12; t++)
            #pragma unroll
            for (int nt = 0; nt < 2; nt++)
                acc[t][nt] = (f32x4){0.f, 0.f, 0.f, 0.f};

        const unsigned short* ap = awp + (size_t)(fhi * 12) * 2 * 512 + lane * 8;
        #pragma unroll
        for (int t = 0; t < 12; t++) {
            #pragma unroll
            for (int ks = 0; ks < 2; ks++) {
                const bf16x8 a = *reinterpret_cast<const bf16x8*>(ap + (t * 2 + ks) * 512);
                #pragma unroll
                for (int nt = 0; nt < 2; nt++) {
                    acc[t][nt] = __builtin_amdgcn_mfma_f32_16x16x32_bf16(
                        a, (t < 6 ? bx[ks][nt] : bhv[ks][nt]), acc[t][nt], 0, 0, 0);
                }
            }
        }

        // pointwise: this thread owns channels f = fhi*16 + kg*4 + r, position
        // p0 + nt*16 + col.
        #pragma unroll
        for (int r = 0; r < 4; r++) {
            const int f = fhi * 16 + kg * 4 + r;
            const float b0 = bih[0*F+f], b1 = bih[1*F+f], b2 = bih[2*F+f];
            const float b3 = bih[3*F+f], b4 = bih[4*F+f], b5 = bih[5*F+f];
            const float bhf = bh[f];
            #pragma unroll
            for (int nt = 0; nt < 2; nt++) {
                const int p = p0 + nt * 16 + col;
                const float gi0 = acc[0][nt][r] + b0;
                const float gi1 = acc[1][nt][r] + b1;
                const float gi2 = acc[2][nt][r] + b2;
                const float gi3 = acc[3][nt][r] + b3;
                const float gi4 = acc[4][nt][r] + b4;
                const float gi5 = acc[5][nt][r] + b5;
                const float gh0 = acc[6][nt][r];
                const float gh1 = acc[7][nt][r];
                const float gh2 = acc[8][nt][r];
                const float gh3 = acc[9][nt][r];
                const float gh4 = acc[10][nt][r];
                const float gh5 = acc[11][nt][r];
                const float ri = sigmoidf_fast(gi0 + gh0);
                const float rh = sigmoidf_fast(gi1 + gh1);
                const float zi = sigmoidf_fast(gi2 + gh2);
                const float zh = sigmoidf_fast(gi3 + gh3);
                const float ci = tanhf_fast(gi5 + rh * (gh5 + bhf));
                const float ch = tanhf_fast(ri * gi4 + gh4);
                const float xf = x[f * SP + p];
                const float hf = h[f * SP + p];
                out [f * SP + p] = zi * ch + (1.0f - zi) * xf;
                hnew[f * SP + p] = zh * ci + (1.0f - zh) * hf;
            }
        }
    }
}

// ---------------------------------------------------------------------------
extern "C" void kernel_launch(void* const* d_in, const int* in_sizes, int n_in,
                              void* d_out, int out_size, void* d_ws, size_t ws_size,
                              hipStream_t stream) {
    const float* x       = (const float*)d_in[0];
    const float* h1      = (const float*)d_in[1];
    const float* h2      = (const float*)d_in[2];
    const float* win_w1  = (const float*)d_in[3];
    const float* win_b1  = (const float*)d_in[4];
    const float* win_w2  = (const float*)d_in[5];
    const float* win_b2  = (const float*)d_in[6];
    const float* r1_wih  = (const float*)d_in[7];
    const float* r1_bih  = (const float*)d_in[8];
    const float* r1_whh  = (const float*)d_in[9];
    const float* r1_bh   = (const float*)d_in[10];
    const float* wbt_w1  = (const float*)d_in[11];
    const float* wbt_b1  = (const float*)d_in[12];
    const float* wbt_w2  = (const float*)d_in[13];
    const float* wbt_b2  = (const float*)d_in[14];
    const float* r2_wih  = (const float*)d_in[15];
    const float* r2_bih  = (const float*)d_in[16];
    const float* r2_whh  = (const float*)d_in[17];
    const float* r2_bh   = (const float*)d_in[18];
    const float* wout_w1 = (const float*)d_in[19];
    const float* wout_b1 = (const float*)d_in[20];
    const float* wout_w2 = (const float*)d_in[21];
    const float* wout_b2 = (const float*)d_in[22];

    float* eta_out = (float*)d_out;                       // 2*SP
    float* h1n_out = eta_out + 2 * SP;                    // 64*SP
    float* h2n_out = h1n_out + F * SP;                    // 64*SP

    float* bufA = (float*)d_ws;
    float* bufB = bufA + (size_t)F * SP;

    // Repacked weights live in the eta region of d_out (221184 floats); it is
    // dead until the final kernel overwrites it.
    unsigned short* lru1_awp = (unsigned short*)eta_out;            // 49152 u16 = 24576 f
    unsigned short* lru2_awp = (unsigned short*)(eta_out + 24576);  // 49152 u16
    float* wbt1_p  = eta_out + 49152;      // 36864
    float* wout1_p = eta_out + 86016;      // 36864
    float* win1_p  = eta_out + 122880;     // 2304
    float* win2_p  = eta_out + 125184;     // 12288
    float* wbt2_p  = eta_out + 137472;     // 12288 (ends 149760 < 221184)

    const dim3 blk(256);

    // --- repacks ---
    repack_lru_frag<<<192, blk, 0, stream>>>(r1_wih, r1_whh, lru1_awp);
    repack_lru_frag<<<192, blk, 0, stream>>>(r2_wih, r2_whh, lru2_awp);
    repack_sp<64><<<144, blk, 0, stream>>>(wbt_w1, wbt1_p);
    repack_sp<64><<<144, blk, 0, stream>>>(wout_w1, wout1_p);
    repack_sp<4><<<9, blk, 0, stream>>>(win_w1, win1_p);
    repack_tm<<<48, blk, 0, stream>>>(win_w2, win2_p);
    repack_tm<<<48, blk, 0, stream>>>(wbt_w2, wbt2_p);

    const dim3 gA(SP / 256, F / 8);         // conv_spatial2, NF=8
    const dim3 gB(PLANE / 256, F / 8);      // conv_temporal2, NF=8
    const dim3 gL(SP / 128);                // lru_mfma: 4 waves x 32 pos

    // block 1 (win): 4 -> 64
    conv_spatial2<4, 8><<<gA, blk, 0, stream>>>(x, win1_p, win_b1, bufA);
    conv_temporal2<8><<<gB, blk, 0, stream>>>(bufA, win2_p, win_b2, bufB);
    // LRU 1: y=bufB, h1 -> out=bufA, hnew=h1n
    lru_mfma<<<gL, blk, 0, stream>>>(bufB, h1, lru1_awp, r1_bih, r1_bh,
                                     bufA, h1n_out);
    // block 2 (wbt): 64 -> 64
    conv_spatial2<64, 8><<<gA, blk, 0, stream>>>(bufA, wbt1_p, wbt_b1, bufB);
    conv_temporal2<8><<<gB, blk, 0, stream>>>(bufB, wbt2_p, wbt_b2, bufA);
    // LRU 2: y=bufA, h2 -> out=bufB, hnew=h2n
    lru_mfma<<<gL, blk, 0, stream>>>(bufA, h2, lru2_awp, r2_bih, r2_bh,
                                     bufB, h2n_out);
    // block 3 (wout): 64 -> 64 -> 2, no final relu
    conv_spatial2<64, 8><<<gA, blk, 0, stream>>>(bufB, wout1_p, wout_b1, bufA);
    conv_temporal_out<<<dim3(PLANE / 256), blk, 0, stream>>>(
        bufA, wout_w2, wout_b2, eta_out);
}

// Round 4
// 245.696 us; speedup vs baseline: 5.9345x; 2.4456x over previous
//
#include <hip/hip_runtime.h>

#define TT 12
#define DD 96
#define WW 96
#define PLANE (DD*WW)      // 9216
#define SP (TT*PLANE)      // 110592
#define F 64

typedef short bf16x8 __attribute__((ext_vector_type(8)));
typedef short bf16x4 __attribute__((ext_vector_type(4)));
typedef float f32x4  __attribute__((ext_vector_type(4)));

__device__ __forceinline__ float sigmoidf_fast(float x){
    return 1.0f / (1.0f + __expf(-x));
}
__device__ __forceinline__ float tanhf_fast(float x){
    x = fminf(15.0f, fmaxf(-15.0f, x));
    float e = __expf(2.0f * x);
    return (e - 1.0f) / (e + 1.0f);
}
__device__ __forceinline__ unsigned short f2bf(float x){
    unsigned int u = __float_as_uint(x);
    u = (u + 0x7FFFu + ((u >> 16) & 1u)) >> 16;   // RNE
    return (unsigned short)u;
}
__device__ __forceinline__ float bf2f(unsigned short u){
    return __uint_as_float(((unsigned int)u) << 16);
}

// ===========================================================================
// Repack kernels (every call; tiny).
// ===========================================================================
// LRU weights -> bf16 A-fragments. frag = (fhi*12 + t)*2 + ks
// t 0..5: Wih gate t ; 6..11: Whh gate t-6.
// m = gate*64 + fhi*16 + (lane&15) ; kk = ks*32 + (lane>>4)*8 + j.
__global__ __launch_bounds__(256) void repack_lru_frag(
    const float* __restrict__ wih, const float* __restrict__ whh,
    unsigned short* __restrict__ awp)
{
    const int idx  = blockIdx.x * 256 + threadIdx.x;  // 49152
    const int j    = idx & 7;
    const int lane = (idx >> 3) & 63;
    const int frag = idx >> 9;
    const int ks   = frag & 1;
    const int t    = (frag >> 1) % 12;
    const int fhi  = frag / 24;
    const int g    = (t < 6) ? t : t - 6;
    const int m    = g * 64 + fhi * 16 + (lane & 15);
    const int kk   = ks * 32 + (lane >> 4) * 8 + j;
    const float v  = (t < 6) ? wih[m * F + kk] : whh[m * F + kk];
    awp[idx] = f2bf(v);
}

// spatial 3x3 conv weights (64,64,1,3,3) -> bf16 A-frags, frag=(tap*2+cl)*4+fhi
__global__ __launch_bounds__(256) void repack_sp_frag(
    const float* __restrict__ wgt, unsigned short* __restrict__ afr)
{
    const int idx  = blockIdx.x * 256 + threadIdx.x;  // 18*4*512 = 36864
    const int j    = idx & 7;
    const int lane = (idx >> 3) & 63;
    const int frag = idx >> 9;
    const int fhi  = frag & 3;
    const int cl   = (frag >> 2) & 1;
    const int tap  = frag >> 3;
    const int f    = fhi * 16 + (lane & 15);
    const int c    = cl * 32 + (lane >> 4) * 8 + j;
    afr[idx] = f2bf(wgt[(f * 64 + c) * 9 + tap]);
}

// temporal 3-tap conv weights (64,64,3) -> bf16 A-frags, frag=(dt*2+cl)*4+fhi
__global__ __launch_bounds__(256) void repack_tm_frag(
    const float* __restrict__ wgt, unsigned short* __restrict__ afr)
{
    const int idx  = blockIdx.x * 256 + threadIdx.x;  // 6*4*512 = 12288
    const int j    = idx & 7;
    const int lane = (idx >> 3) & 63;
    const int frag = idx >> 9;
    const int fhi  = frag & 3;
    const int cl   = (frag >> 2) & 1;
    const int dt   = frag >> 3;
    const int f    = fhi * 16 + (lane & 15);
    const int c    = cl * 32 + (lane >> 4) * 8 + j;
    afr[idx] = f2bf(wgt[(f * 64 + c) * 3 + dt]);
}

// first conv weights (64,4,1,3,3) -> f32 wp[c][tap][f]
__global__ __launch_bounds__(256) void repack_sp4(
    const float* __restrict__ wgt, float* __restrict__ wp)
{
    const int idx = blockIdx.x * 256 + threadIdx.x;  // 4*9*64 = 2304
    if (idx >= 4 * 9 * 64) return;
    const int f = idx & 63;
    const int tap = (idx >> 6) % 9;
    const int c = idx / (9 * 64);
    wp[idx] = wgt[((f * 4) + c) * 9 + tap];
}

// ===========================================================================
// First conv: CIN=4, f32 [c][p] input, scalar FMA, bf16 [p][c] output, relu.
// ===========================================================================
__global__ __launch_bounds__(256) void conv_spatial_in(
    const float* __restrict__ x, const float* __restrict__ wp,
    const float* __restrict__ bias, unsigned short* __restrict__ out)
{
    const int p  = blockIdx.x * 256 + threadIdx.x;
    const int f0 = blockIdx.y * 16;
    const int t  = p / PLANE;
    const int r  = p - t * PLANE;
    const int d  = r / WW;
    const int w  = r - d * WW;
    const int dm = (d > 0    ? d - 1 : 0);
    const int dp = (d < DD-1 ? d + 1 : DD-1);
    const int wm = (w > 0    ? w - 1 : 0);
    const int wpx= (w < WW-1 ? w + 1 : WW-1);

    float acc[16];
    #pragma unroll
    for (int j = 0; j < 16; j++) acc[j] = 0.f;

    const int base = t * PLANE;
    for (int c = 0; c < 4; c++) {
        const float* ip = x + c * SP + base;
        const float v0 = ip[dm*WW+wm], v1 = ip[dm*WW+w], v2 = ip[dm*WW+wpx];
        const float v3 = ip[d *WW+wm], v4 = ip[d *WW+w], v5 = ip[d *WW+wpx];
        const float v6 = ip[dp*WW+wm], v7 = ip[dp*WW+w], v8 = ip[dp*WW+wpx];
        const float* wr = wp + c * 9 * 64 + f0;
        #pragma unroll
        for (int j = 0; j < 16; j++) {
            acc[j] += v0*wr[0*64+j] + v1*wr[1*64+j] + v2*wr[2*64+j]
                    + v3*wr[3*64+j] + v4*wr[4*64+j] + v5*wr[5*64+j]
                    + v6*wr[6*64+j] + v7*wr[7*64+j] + v8*wr[8*64+j];
        }
    }
    bf16x8 pk[2];
    #pragma unroll
    for (int j = 0; j < 16; j++) {
        float val = fmaxf(acc[j] + bias[f0 + j], 0.f);
        pk[j >> 3][j & 7] = (short)f2bf(val);
    }
    *(bf16x8*)(out + (size_t)p * 64 + f0)     = pk[0];
    *(bf16x8*)(out + (size_t)p * 64 + f0 + 8) = pk[1];
}

// ===========================================================================
// Spatial 3x3 conv via MFMA, edge clamp, bias+relu. bf16 [p][c] in/out.
// Wave = one (t,d) row segment of 32 w. K = 9 taps x 64 c (18 slices).
// ===========================================================================
__global__ __launch_bounds__(256) void conv_sp_mfma(
    const unsigned short* __restrict__ in, const unsigned short* __restrict__ afr,
    const float* __restrict__ bias, unsigned short* __restrict__ out)
{
    const int tid  = threadIdx.x;
    const int wave = tid >> 6;
    const int lane = tid & 63;
    const int col  = lane & 15;
    const int kg   = lane >> 4;
    const int wg   = blockIdx.x * 4 + wave;      // 0..3455
    const int row  = wg / 3;
    const int wseg = wg - row * 3;
    const int t    = row / DD;
    const int d    = row - t * DD;
    const int w0   = wseg * 32;

    int wn[2];
    wn[0] = w0 + col;
    wn[1] = w0 + 16 + col;
    int voff[2][3];   // u16 units: wclamp*64 + kg*8 (fully unrolled -> regs)
    #pragma unroll
    for (int nt = 0; nt < 2; nt++)
        #pragma unroll
        for (int dwi = 0; dwi < 3; dwi++) {
            int wc = wn[nt] + dwi - 1;
            wc = min(max(wc, 0), WW - 1);
            voff[nt][dwi] = wc * 64 + kg * 8;
        }

    f32x4 acc[4][2];
    #pragma unroll
    for (int fhi = 0; fhi < 4; fhi++)
        #pragma unroll
        for (int nt = 0; nt < 2; nt++)
            acc[fhi][nt] = (f32x4){0.f, 0.f, 0.f, 0.f};

    const int tb = t * PLANE;
    #pragma unroll
    for (int ddi = 0; ddi < 3; ddi++) {
        int dr = d + ddi - 1;
        dr = min(max(dr, 0), DD - 1);
        const unsigned short* rp = in + (size_t)(tb + dr * WW) * 64;
        #pragma unroll
        for (int dwi = 0; dwi < 3; dwi++) {
            const int tap = ddi * 3 + dwi;
            #pragma unroll
            for (int cl = 0; cl < 2; cl++) {
                const bf16x8 b0 = *(const bf16x8*)(rp + voff[0][dwi] + cl * 32);
                const bf16x8 b1 = *(const bf16x8*)(rp + voff[1][dwi] + cl * 32);
                const unsigned short* ap = afr + (size_t)((tap * 2 + cl) * 4) * 512 + lane * 8;
                #pragma unroll
                for (int fhi = 0; fhi < 4; fhi++) {
                    const bf16x8 a = *(const bf16x8*)(ap + fhi * 512);
                    acc[fhi][0] = __builtin_amdgcn_mfma_f32_16x16x32_bf16(a, b0, acc[fhi][0], 0, 0, 0);
                    acc[fhi][1] = __builtin_amdgcn_mfma_f32_16x16x32_bf16(a, b1, acc[fhi][1], 0, 0, 0);
                }
            }
        }
    }

    const int pbase = tb + d * WW;
    #pragma unroll
    for (int fhi = 0; fhi < 4; fhi++) {
        const float4 bv = *(const float4*)(bias + fhi * 16 + kg * 4);
        #pragma unroll
        for (int nt = 0; nt < 2; nt++) {
            const int p = pbase + wn[nt];
            bf16x4 pk;
            pk[0] = (short)f2bf(fmaxf(acc[fhi][nt][0] + bv.x, 0.f));
            pk[1] = (short)f2bf(fmaxf(acc[fhi][nt][1] + bv.y, 0.f));
            pk[2] = (short)f2bf(fmaxf(acc[fhi][nt][2] + bv.z, 0.f));
            pk[3] = (short)f2bf(fmaxf(acc[fhi][nt][3] + bv.w, 0.f));
            *(bf16x4*)(out + (size_t)p * 64 + fhi * 16 + kg * 4) = pk;
        }
    }
}

// ===========================================================================
// Temporal 3-tap conv via MFMA, wrap pad, bias+relu. bf16 [p][c] in/out.
// Wave = 32 consecutive p2 at fixed t. K = 3 dt x 64 c (6 slices).
// ===========================================================================
__global__ __launch_bounds__(256) void conv_tm_mfma(
    const unsigned short* __restrict__ in, const unsigned short* __restrict__ afr,
    const float* __restrict__ bias, unsigned short* __restrict__ out)
{
    const int tid  = threadIdx.x;
    const int wave = tid >> 6;
    const int lane = tid & 63;
    const int col  = lane & 15;
    const int kg   = lane >> 4;
    const int wg   = blockIdx.x * 4 + wave;      // 0..3455
    const int t    = wg / 288;
    const int seg  = wg - t * 288;
    const int p20  = seg * 32;

    f32x4 acc[4][2];
    #pragma unroll
    for (int fhi = 0; fhi < 4; fhi++)
        #pragma unroll
        for (int nt = 0; nt < 2; nt++)
            acc[fhi][nt] = (f32x4){0.f, 0.f, 0.f, 0.f};

    #pragma unroll
    for (int dt = 0; dt < 3; dt++) {
        const int tsrc = (t + dt + 11) % 12;
        const unsigned short* bp = in + (size_t)(tsrc * PLANE + p20 + col) * 64 + kg * 8;
        #pragma unroll
        for (int cl = 0; cl < 2; cl++) {
            const bf16x8 b0 = *(const bf16x8*)(bp + cl * 32);
            const bf16x8 b1 = *(const bf16x8*)(bp + 16 * 64 + cl * 32);
            const unsigned short* ap = afr + (size_t)((dt * 2 + cl) * 4) * 512 + lane * 8;
            #pragma unroll
            for (int fhi = 0; fhi < 4; fhi++) {
                const bf16x8 a = *(const bf16x8*)(ap + fhi * 512);
                acc[fhi][0] = __builtin_amdgcn_mfma_f32_16x16x32_bf16(a, b0, acc[fhi][0], 0, 0, 0);
                acc[fhi][1] = __builtin_amdgcn_mfma_f32_16x16x32_bf16(a, b1, acc[fhi][1], 0, 0, 0);
            }
        }
    }

    const int pbase = t * PLANE + p20;
    #pragma unroll
    for (int fhi = 0; fhi < 4; fhi++) {
        const float4 bv = *(const float4*)(bias + fhi * 16 + kg * 4);
        #pragma unroll
        for (int nt = 0; nt < 2; nt++) {
            const int p = pbase + nt * 16 + col;
            bf16x4 pk;
            pk[0] = (short)f2bf(fmaxf(acc[fhi][nt][0] + bv.x, 0.f));
            pk[1] = (short)f2bf(fmaxf(acc[fhi][nt][1] + bv.y, 0.f));
            pk[2] = (short)f2bf(fmaxf(acc[fhi][nt][2] + bv.z, 0.f));
            pk[3] = (short)f2bf(fmaxf(acc[fhi][nt][3] + bv.w, 0.f));
            *(bf16x4*)(out + (size_t)p * 64 + fhi * 16 + kg * 4) = pk;
        }
    }
}

// ===========================================================================
// LRU via MFMA. x: bf16 [p][c]; h: f32 [c][p]; out: bf16 [p][c];
// hnew: f32 [c][p] (final output region).
// ===========================================================================
__global__ __launch_bounds__(256) void lru_mfma2(
    const unsigned short* __restrict__ x, const float* __restrict__ h,
    const unsigned short* __restrict__ awp,
    const float* __restrict__ bih, const float* __restrict__ bh,
    unsigned short* __restrict__ out, float* __restrict__ hnew)
{
    const int tid  = threadIdx.x;
    const int wave = tid >> 6;
    const int lane = tid & 63;
    const int col  = lane & 15;
    const int kg   = lane >> 4;
    const int p0   = (blockIdx.x * 4 + wave) * 32;

    bf16x8 bx[2][2], bhv[2][2];
    #pragma unroll
    for (int ks = 0; ks < 2; ks++) {
        #pragma unroll
        for (int nt = 0; nt < 2; nt++) {
            const int pb = p0 + nt * 16 + col;
            bx[ks][nt] = *(const bf16x8*)(x + (size_t)pb * 64 + ks * 32 + kg * 8);
            bf16x8 vh;
            #pragma unroll
            for (int j = 0; j < 8; j++) {
                const int k = ks * 32 + kg * 8 + j;
                vh[j] = (short)f2bf(h[(size_t)k * SP + pb]);
            }
            bhv[ks][nt] = vh;
        }
    }

    #pragma unroll
    for (int fhi = 0; fhi < 4; fhi++) {
        f32x4 acc[12][2];
        #pragma unroll
        for (int t = 0; t < 12; t++)
            #pragma unroll
            for (int nt = 0; nt < 2; nt++)
                acc[t][nt] = (f32x4){0.f, 0.f, 0.f, 0.f};

        const unsigned short* ap = awp + (size_t)(fhi * 12) * 2 * 512 + lane * 8;
        #pragma unroll
        for (int t = 0; t < 12; t++) {
            #pragma unroll
            for (int ks = 0; ks < 2; ks++) {
                const bf16x8 a = *(const bf16x8*)(ap + (t * 2 + ks) * 512);
                #pragma unroll
                for (int nt = 0; nt < 2; nt++) {
                    acc[t][nt] = __builtin_amdgcn_mfma_f32_16x16x32_bf16(
                        a, (t < 6 ? bx[ks][nt] : bhv[ks][nt]), acc[t][nt], 0, 0, 0);
                }
            }
        }

        const int f0 = fhi * 16 + kg * 4;
        const float4 b0v = *(const float4*)(bih + 0*F + f0);
        const float4 b1v = *(const float4*)(bih + 1*F + f0);
        const float4 b2v = *(const float4*)(bih + 2*F + f0);
        const float4 b3v = *(const float4*)(bih + 3*F + f0);
        const float4 b4v = *(const float4*)(bih + 4*F + f0);
        const float4 b5v = *(const float4*)(bih + 5*F + f0);
        const float4 bhv4 = *(const float4*)(bh + f0);
        const float b0a[4] = {b0v.x, b0v.y, b0v.z, b0v.w};
        const float b1a[4] = {b1v.x, b1v.y, b1v.z, b1v.w};
        const float b2a[4] = {b2v.x, b2v.y, b2v.z, b2v.w};
        const float b3a[4] = {b3v.x, b3v.y, b3v.z, b3v.w};
        const float b4a[4] = {b4v.x, b4v.y, b4v.z, b4v.w};
        const float b5a[4] = {b5v.x, b5v.y, b5v.z, b5v.w};
        const float bha[4] = {bhv4.x, bhv4.y, bhv4.z, bhv4.w};

        #pragma unroll
        for (int nt = 0; nt < 2; nt++) {
            const int p = p0 + nt * 16 + col;
            const bf16x4 xv4 = *(const bf16x4*)(x + (size_t)p * 64 + f0);
            bf16x4 opk;
            #pragma unroll
            for (int r = 0; r < 4; r++) {
                const int f = f0 + r;
                const float ri = sigmoidf_fast(acc[0][nt][r] + b0a[r] + acc[6][nt][r]);
                const float rh = sigmoidf_fast(acc[1][nt][r] + b1a[r] + acc[7][nt][r]);
                const float zi = sigmoidf_fast(acc[2][nt][r] + b2a[r] + acc[8][nt][r]);
                const float zh = sigmoidf_fast(acc[3][nt][r] + b3a[r] + acc[9][nt][r]);
                const float ci = tanhf_fast(acc[5][nt][r] + b5a[r] + rh * (acc[11][nt][r] + bha[r]));
                const float ch = tanhf_fast(ri * (acc[4][nt][r] + b4a[r]) + acc[10][nt][r]);
                const float xf = bf2f((unsigned short)xv4[r]);
                const float hf = h[(size_t)f * SP + p];
                opk[r] = (short)f2bf(zi * ch + (1.0f - zi) * xf);
                hnew[(size_t)f * SP + p] = zh * ci + (1.0f - zh) * hf;
            }
            *(bf16x4*)(out + (size_t)p * 64 + f0) = opk;
        }
    }
}

// ===========================================================================
// Final temporal conv, COUT=2, no relu. bf16 [p][c] in, f32 [j][p] out.
// ===========================================================================
__global__ __launch_bounds__(256) void conv_tm_out(
    const unsigned short* __restrict__ in, const float* __restrict__ wgt,
    const float* __restrict__ bias, float* __restrict__ out)
{
    const int p  = blockIdx.x * 256 + threadIdx.x;  // 0..SP-1
    const int t  = p / PLANE;
    const int p2 = p - t * PLANE;
    const size_t im = (size_t)(((t + 11) % 12) * PLANE + p2) * 64;
    const size_t ic = (size_t)p * 64;
    const size_t ip = (size_t)(((t + 1) % 12) * PLANE + p2) * 64;

    float acc0 = 0.f, acc1 = 0.f;
    for (int c0 = 0; c0 < 64; c0 += 8) {
        const bf16x8 vm = *(const bf16x8*)(in + im + c0);
        const bf16x8 vc = *(const bf16x8*)(in + ic + c0);
        const bf16x8 vp = *(const bf16x8*)(in + ip + c0);
        #pragma unroll
        for (int jj = 0; jj < 8; jj++) {
            const int c = c0 + jj;
            const float fm = bf2f((unsigned short)vm[jj]);
            const float fc = bf2f((unsigned short)vc[jj]);
            const float fp = bf2f((unsigned short)vp[jj]);
            const float* w0 = wgt + (0 * 64 + c) * 3;
            const float* w1 = wgt + (1 * 64 + c) * 3;
            acc0 += fm * w0[0] + fc * w0[1] + fp * w0[2];
            acc1 += fm * w1[0] + fc * w1[1] + fp * w1[2];
        }
    }
    out[0 * SP + p] = acc0 + bias[0];
    out[1 * SP + p] = acc1 + bias[1];
}

// ===========================================================================
extern "C" void kernel_launch(void* const* d_in, const int* in_sizes, int n_in,
                              void* d_out, int out_size, void* d_ws, size_t ws_size,
                              hipStream_t stream) {
    const float* x       = (const float*)d_in[0];
    const float* h1      = (const float*)d_in[1];
    const float* h2      = (const float*)d_in[2];
    const float* win_w1  = (const float*)d_in[3];
    const float* win_b1  = (const float*)d_in[4];
    const float* win_w2  = (const float*)d_in[5];
    const float* win_b2  = (const float*)d_in[6];
    const float* r1_wih  = (const float*)d_in[7];
    const float* r1_bih  = (const float*)d_in[8];
    const float* r1_whh  = (const float*)d_in[9];
    const float* r1_bh   = (const float*)d_in[10];
    const float* wbt_w1  = (const float*)d_in[11];
    const float* wbt_b1  = (const float*)d_in[12];
    const float* wbt_w2  = (const float*)d_in[13];
    const float* wbt_b2  = (const float*)d_in[14];
    const float* r2_wih  = (const float*)d_in[15];
    const float* r2_bih  = (const float*)d_in[16];
    const float* r2_whh  = (const float*)d_in[17];
    const float* r2_bh   = (const float*)d_in[18];
    const float* wout_w1 = (const float*)d_in[19];
    const float* wout_b1 = (const float*)d_in[20];
    const float* wout_w2 = (const float*)d_in[21];
    const float* wout_b2 = (const float*)d_in[22];

    float* eta_out = (float*)d_out;                       // 2*SP
    float* h1n_out = eta_out + 2 * SP;                    // 64*SP f32 [c][p]
    float* h2n_out = h1n_out + F * SP;

    // workspace: two bf16 [p][c] activation buffers + weight fragments
    unsigned short* bufA = (unsigned short*)d_ws;         // SP*64 u16
    unsigned short* bufB = bufA + (size_t)SP * 64;
    unsigned short* lru1_awp = bufB + (size_t)SP * 64;    // 49152
    unsigned short* lru2_awp = lru1_awp + 49152;          // 49152
    unsigned short* wbt1_f   = lru2_awp + 49152;          // 36864
    unsigned short* wout1_f  = wbt1_f + 36864;            // 36864
    unsigned short* win2_f   = wout1_f + 36864;           // 12288
    unsigned short* wbt2_f   = win2_f + 12288;            // 12288
    float*          win1_p   = (float*)(wbt2_f + 12288);  // 2304 f32

    const dim3 blk(256);

    // --- repacks ---
    repack_lru_frag<<<192, blk, 0, stream>>>(r1_wih, r1_whh, lru1_awp);
    repack_lru_frag<<<192, blk, 0, stream>>>(r2_wih, r2_whh, lru2_awp);
    repack_sp_frag<<<144, blk, 0, stream>>>(wbt_w1, wbt1_f);
    repack_sp_frag<<<144, blk, 0, stream>>>(wout_w1, wout1_f);
    repack_tm_frag<<<48, blk, 0, stream>>>(win_w2, win2_f);
    repack_tm_frag<<<48, blk, 0, stream>>>(wbt_w2, wbt2_f);
    repack_sp4<<<9, blk, 0, stream>>>(win_w1, win1_p);

    const dim3 gIn(SP / 256, 4);     // conv_spatial_in, NF=16
    const dim3 gM(864);              // 3456 waves, 4/block (sp/tm/lru mfma)

    // block 1 (win): 4 -> 64
    conv_spatial_in<<<gIn, blk, 0, stream>>>(x, win1_p, win_b1, bufA);
    conv_tm_mfma<<<gM, blk, 0, stream>>>(bufA, win2_f, win_b2, bufB);
    // LRU 1
    lru_mfma2<<<gM, blk, 0, stream>>>(bufB, h1, lru1_awp, r1_bih, r1_bh,
                                      bufA, h1n_out);
    // block 2 (wbt)
    conv_sp_mfma<<<gM, blk, 0, stream>>>(bufA, wbt1_f, wbt_b1, bufB);
    conv_tm_mfma<<<gM, blk, 0, stream>>>(bufB, wbt2_f, wbt_b2, bufA);
    // LRU 2
    lru_mfma2<<<gM, blk, 0, stream>>>(bufA, h2, lru2_awp, r2_bih, r2_bh,
                                      bufB, h2n_out);
    // block 3 (wout): spatial -> 2-channel temporal, no relu
    conv_sp_mfma<<<gM, blk, 0, stream>>>(bufB, wout1_f, wout_b1, bufA);
    conv_tm_out<<<dim3(SP / 256), blk, 0, stream>>>(
        bufA, wout_w2, wout_b2, eta_out);
}